// Round 8
// baseline (867.041 us; speedup 1.0000x reference)
//
#include <hip/hip_runtime.h>
#include <math.h>

namespace {
constexpr int cB = 16, cN = 8192, cC = 64, cK = 128, cR = 4, cNL = 4;
constexpr float kTwoPi = 6.28318530717958647692f;

// workspace layout (float offsets)
constexpr size_t OFF_H     = 0;                                // 8,388,608
constexpr size_t OFF_PACKA = (size_t)cB * cC * cN;             // +524,288
constexpr size_t OFF_PACKB = OFF_PACKA + (size_t)cB * cN * 4;  // +524,288
constexpr size_t OFF_PACKC = OFF_PACKB + (size_t)cB * cN * 4;  // +262,144
constexpr size_t OFF_PC    = OFF_PACKC + (size_t)cB * cN * 2;  // 512 slots * 8192
constexpr size_t OFF_PS    = OFF_PC + (size_t)512 * 8192;
constexpr size_t OFF_XC    = OFF_PS + (size_t)512 * 8192;
constexpr size_t OFF_XS    = OFF_XC + (size_t)cB * cC * cK;
constexpr size_t OFF_FCT   = OFF_XS + (size_t)cB * cC * cK;
constexpr size_t OFF_FST   = OFF_FCT + (size_t)cB * cK * cC;
constexpr size_t OFF_F0    = OFF_FST + (size_t)cB * cK * cC;
// end = 18,613,248 floats = 74.5 MB

__device__ __forceinline__ float gelu_f(float x) {
  return 0.5f * x * (1.0f + erff(x * 0.7071067811865475244f));
}

struct cpx { float x, y; };
__device__ __forceinline__ cpx cmul(cpx a, cpx b) {
  cpx r;
  r.x = fmaf(a.x, b.x, -(a.y * b.y));
  r.y = fmaf(a.x, b.y, a.y * b.x);
  return r;
}

// thread g (0..7) produces modes k = 8g+ky and 64+8g+ky (ky=0..7) for one point,
// scaled by wsz (quadrature weight folded into the bases).
__device__ __forceinline__ void compute_modes_w(int g, float4 pA, float4 pB, float wsz,
                                                float* cw_row, float* sw_row) {
  cpx ex{pA.x, pA.y}, ey{pA.z, pA.w}, ex8{pB.x, pB.y}, ey4{pB.z, pB.w};
  cpx eyp[8];
  eyp[0] = {1.0f, 0.0f};
  eyp[1] = ey;
  eyp[2] = cmul(ey, ey);
  eyp[3] = cmul(eyp[2], ey);
  eyp[4] = ey4;
  eyp[5] = cmul(ey4, ey);
  eyp[6] = cmul(ey4, eyp[2]);
  eyp[7] = cmul(ey4, eyp[3]);
  cpx r{1.0f, 0.0f};
  cpx t = ex;
  if (g & 1) r = t;
  t = cmul(t, t);
  if (g & 2) r = cmul(r, t);
  t = cmul(t, t);
  if (g & 4) r = cmul(r, t);
  r.x *= wsz; r.y *= wsz;       // fold weight: scales all 16 modes of this thread
  cpx r8 = cmul(r, ex8);
  float mc[8], msn[8], mc2[8], msn2[8];
#pragma unroll
  for (int ky = 0; ky < 8; ky++) {
    cpx m1 = cmul(r, eyp[ky]);
    cpx m2 = cmul(r8, eyp[ky]);
    mc[ky] = m1.x; msn[ky] = m1.y;
    mc2[ky] = m2.x; msn2[ky] = m2.y;
  }
  *(float4*)&cw_row[8 * g]          = make_float4(mc[0], mc[1], mc[2], mc[3]);
  *(float4*)&cw_row[8 * g + 4]      = make_float4(mc[4], mc[5], mc[6], mc[7]);
  *(float4*)&cw_row[64 + 8 * g]     = make_float4(mc2[0], mc2[1], mc2[2], mc2[3]);
  *(float4*)&cw_row[64 + 8 * g + 4] = make_float4(mc2[4], mc2[5], mc2[6], mc2[7]);
  *(float4*)&sw_row[8 * g]          = make_float4(msn[0], msn[1], msn[2], msn[3]);
  *(float4*)&sw_row[8 * g + 4]      = make_float4(msn[4], msn[5], msn[6], msn[7]);
  *(float4*)&sw_row[64 + 8 * g]     = make_float4(msn2[0], msn2[1], msn2[2], msn2[3]);
  *(float4*)&sw_row[64 + 8 * g + 4] = make_float4(msn2[4], msn2[5], msn2[6], msn2[7]);
}
}  // namespace

// --- prep: fc0 into (B,C,N), per-point phase factors
__global__ void __launch_bounds__(256) k_prep(const float* __restrict__ x,
                                              const float* __restrict__ fc0_w,
                                              const float* __restrict__ fc0_b,
                                              float* __restrict__ ws) {
  int t = blockIdx.x * 256 + threadIdx.x;
  int b = t >> 13;
  int n = t & (cN - 1);
  const float* xp = x + (size_t)t * 7;
  float f0 = xp[0], f1 = xp[1], f2 = xp[2];
  float gx = xp[3], gy = xp[4], w = xp[5], m = xp[6];
  float ax = kTwoPi * gx, ay = kTwoPi * gy;
  float sx, cx, sy, cy, s8x, c8x, s4y, c4y;
  sincosf(ax, &sx, &cx);
  sincosf(ay, &sy, &cy);
  sincosf(8.0f * ax, &s8x, &c8x);
  sincosf(4.0f * ay, &s4y, &c4y);
  ((float4*)(ws + OFF_PACKA))[t] = make_float4(cx, sx, cy, sy);
  ((float4*)(ws + OFF_PACKB))[t] = make_float4(c8x, s8x, c4y, s4y);
  ((float2*)(ws + OFF_PACKC))[t] = make_float2(w * (float)cN * m, m);
  float* h = ws + OFF_H + (size_t)b * cC * cN + n;
#pragma unroll
  for (int c = 0; c < cC; c++) {
    float v = fc0_b[c] + f0 * fc0_w[c] + f1 * fc0_w[cC + c] + f2 * fc0_w[2 * cC + c];
    h[(size_t)c * cN] = v;
  }
}

// --- forward: double-buffered bases in LDS; h from global (L1 broadcast)
__global__ void __launch_bounds__(256) k_forward(const float* __restrict__ hg,
                                                 const float* __restrict__ ws,
                                                 float* __restrict__ Pc,
                                                 float* __restrict__ Ps) {
  __shared__ __align__(16) float cw[2][32 * 132];  // [buf][s][k], weight folded
  __shared__ __align__(16) float sw[2][32 * 132];
  int b = blockIdx.y, nb = blockIdx.x;  // nb 0..31
  int n_base = nb * 256;
  int tid = threadIdx.x;
  int g = tid >> 5, nn = tid & 31;   // staging mapping
  int tc = tid >> 5, tkq = tid & 31; // compute: c0=tc*8, k=4tkq+q
  const float4* pA = (const float4*)(ws + OFF_PACKA) + (size_t)b * cN;
  const float4* pB = (const float4*)(ws + OFF_PACKB) + (size_t)b * cN;
  const float2* pC = (const float2*)(ws + OFF_PACKC) + (size_t)b * cN;
  const float* hb = hg + (size_t)b * cC * cN;
  float accC[8][4] = {}, accS[8][4] = {};
  // gen tile 0 into buf 0
  {
    float4 a4 = pA[n_base + nn];
    float4 b4 = pB[n_base + nn];
    float wsz = pC[n_base + nn].x;
    compute_modes_w(g, a4, b4, wsz, &cw[0][nn * 132], &sw[0][nn * 132]);
  }
  __syncthreads();
  for (int tile = 0; tile < 8; tile++) {
    int cur = tile & 1;
    int n0 = n_base + tile * 32;
    // prefetch pack for next tile (lands during MAC)
    float4 a4, b4;
    float wsz = 0.0f;
    if (tile < 7) {
      a4 = pA[n0 + 32 + nn];
      b4 = pB[n0 + 32 + nn];
      wsz = pC[n0 + 32 + nn].x;
    }
#pragma unroll 2
    for (int mac = 0; mac < 8; mac++) {
      int s0 = mac * 4;
      float4 h4[8];
#pragma unroll
      for (int j = 0; j < 8; j++)
        h4[j] = *(const float4*)&hb[(size_t)(tc * 8 + j) * cN + n0 + s0];
#pragma unroll
      for (int s4 = 0; s4 < 4; s4++) {
        int s = s0 + s4;
        float4 c4v = *(const float4*)&cw[cur][s * 132 + tkq * 4];
        float4 s4v = *(const float4*)&sw[cur][s * 132 + tkq * 4];
        float cc[4] = {c4v.x, c4v.y, c4v.z, c4v.w};
        float ss[4] = {s4v.x, s4v.y, s4v.z, s4v.w};
#pragma unroll
        for (int j = 0; j < 8; j++) {
          float hv = ((const float*)&h4[j])[s4];
#pragma unroll
          for (int q = 0; q < 4; q++) {
            accC[j][q] = fmaf(hv, cc[q], accC[j][q]);
            accS[j][q] = fmaf(hv, ss[q], accS[j][q]);
          }
        }
      }
    }
    if (tile < 7)
      compute_modes_w(g, a4, b4, wsz, &cw[1 - cur][nn * 132], &sw[1 - cur][nn * 132]);
    __syncthreads();
  }
  float* pcb = Pc + (size_t)(b * 32 + nb) * 8192;
  float* psb = Ps + (size_t)(b * 32 + nb) * 8192;
#pragma unroll
  for (int j = 0; j < 8; j++) {
    int off = (tc * 8 + j) * 128 + tkq * 4;
    *(float4*)&pcb[off] = make_float4(accC[j][0], accC[j][1], accC[j][2], accC[j][3]);
    *(float4*)&psb[off] = make_float4(accS[j][0], accS[j][1], accS[j][2], accS[j][3]);
  }
}

// --- reduce 32 partials -> Xc/Xs
__global__ void __launch_bounds__(256) k_reduce(const float* __restrict__ Pc,
                                                const float* __restrict__ Ps,
                                                float* __restrict__ Xc,
                                                float* __restrict__ Xs) {
  int idx = blockIdx.x * 256 + threadIdx.x;  // 0..131071
  int b = idx >> 13;
  int rest = idx & 8191;
  float sc = 0.0f, ss = 0.0f;
#pragma unroll
  for (int nb = 0; nb < 32; nb++) {
    sc += Pc[(size_t)(b * 32 + nb) * 8192 + rest];
    ss += Ps[(size_t)(b * 32 + nb) * 8192 + rest];
  }
  Xc[idx] = sc;
  Xs[idx] = ss;
}

// --- low-rank mixing; one wave per (b,k); butterfly reduction, no LDS
__global__ void __launch_bounds__(64) k_lowrank(const float* __restrict__ Xc,
                                                const float* __restrict__ Xs,
                                                const float* __restrict__ wc1,
                                                const float* __restrict__ wc2,
                                                const float* __restrict__ ws1,
                                                const float* __restrict__ ws2,
                                                const float* __restrict__ w01,
                                                const float* __restrict__ w02,
                                                float* __restrict__ FcT,
                                                float* __restrict__ FsT,
                                                float* __restrict__ F0, int layer) {
  int b = blockIdx.x;
  int k = blockIdx.y;
  int tid = threadIdx.x;
  const float* xcb = Xc + (size_t)b * cC * cK;
  const float* xsb = Xs + (size_t)b * cC * cK;
  float xcv = xcb[(size_t)tid * cK + k];
  float xsv = -xsb[(size_t)tid * cK + k];
  const float* c1 = wc1 + (size_t)layer * cC * cR * cK + (size_t)tid * cR * cK + k;
  const float* s1 = ws1 + (size_t)layer * cC * cR * cK + (size_t)tid * cR * cK + k;
  float A1[cR], A2[cR], B1[cR], B2[cR];
#pragma unroll
  for (int r = 0; r < cR; r++) {
    float w1c = c1[(size_t)r * cK];
    float w1sv = s1[(size_t)r * cK];
    A1[r] = xcv * w1c;
    A2[r] = xcv * w1sv;
    B1[r] = xsv * w1c;
    B2[r] = xsv * w1sv;
  }
#pragma unroll
  for (int r = 0; r < cR; r++) {
#pragma unroll
    for (int off = 32; off > 0; off >>= 1) {
      A1[r] += __shfl_xor(A1[r], off);
      A2[r] += __shfl_xor(A2[r], off);
      B1[r] += __shfl_xor(B1[r], off);
      B2[r] += __shfl_xor(B2[r], off);
    }
  }
  const float scale = 2.0f / (float)cN;
  const float* c2 = wc2 + (size_t)layer * cR * cC * cK;
  const float* s2 = ws2 + (size_t)layer * cR * cC * cK;
  int o = tid;
  float fc = 0.0f, fs = 0.0f;
#pragma unroll
  for (int r = 0; r < cR; r++) {
    float w2c = c2[((size_t)r * cC + o) * cK + k];
    float w2s = s2[((size_t)r * cC + o) * cK + k];
    fc += A1[r] * w2c - B2[r] * w2s;
    fs += B1[r] * w2c + A2[r] * w2s;
  }
  FcT[((size_t)b * cK + k) * cC + o] = scale * fc;
  FsT[((size_t)b * cK + k) * cC + o] = scale * fs;
  if (k == 0) {
    float t0[cR];
#pragma unroll
    for (int r = 0; r < cR; r++)
      t0[r] = xcv * w01[((size_t)layer * cC + tid) * cR + r];
#pragma unroll
    for (int r = 0; r < cR; r++) {
#pragma unroll
      for (int off = 32; off > 0; off >>= 1) t0[r] += __shfl_xor(t0[r], off);
    }
    float f = 0.0f;
#pragma unroll
    for (int r = 0; r < cR; r++) f += t0[r] * w02[((size_t)layer * cR + r) * cC + o];
    F0[b * cC + o] = f / (float)cN;
  }
}

// --- inverse v4: NO LDS. lane = n-point (64/block), wave = 16-channel slice.
//     Bases in registers; F/F0/wconv/bconv wave-uniform -> scalar loads.
__global__ void __launch_bounds__(256) k_inverse(float* __restrict__ h,
                                                 const float* __restrict__ ws,
                                                 const float* __restrict__ wconv,
                                                 const float* __restrict__ bconv,
                                                 int layer, int do_gelu) {
  int b = blockIdx.y;
  int n_blk = blockIdx.x * 64;
  int tid = threadIdx.x;
  int lane = tid & 63;
  int c0 = __builtin_amdgcn_readfirstlane((tid >> 6) * 16);  // wave-uniform
  int n = n_blk + lane;
  const float4* pA = (const float4*)(ws + OFF_PACKA) + (size_t)b * cN;
  const float4* pB = (const float4*)(ws + OFF_PACKB) + (size_t)b * cN;
  const float2* pC = (const float2*)(ws + OFF_PACKC) + (size_t)b * cN;
  float4 a4 = pA[n];
  float4 b4 = pB[n];
  float mval = pC[n].y;
  cpx ex{a4.x, a4.y}, ey{a4.z, a4.w}, ex8{b4.x, b4.y}, ey4{b4.z, b4.w};
  cpx ex2 = cmul(ex, ex);
  cpx ex3 = cmul(ex2, ex);
  cpx ex4 = cmul(ex2, ex2);
  cpx ex12 = cmul(ex8, ex4);
  cpx eyp[8];
  eyp[0] = {1.0f, 0.0f};
  eyp[1] = ey;
  eyp[2] = cmul(ey, ey);
  eyp[3] = cmul(eyp[2], ey);
  eyp[4] = ey4;
  eyp[5] = cmul(ey4, ey);
  eyp[6] = cmul(ey4, eyp[2]);
  eyp[7] = cmul(ey4, eyp[3]);
  const float* FcB = ws + OFF_FCT + (size_t)b * cK * cC + c0;  // uniform rows
  const float* FsB = ws + OFF_FST + (size_t)b * cK * cC + c0;
  float acc[16] = {};
#pragma unroll
  for (int kx = 0; kx < 16; kx++) {
    cpx base = (kx < 4) ? cpx{1.0f, 0.0f} : (kx < 8) ? ex4 : (kx < 12) ? ex8 : ex12;
    cpx rx;
    int r4 = kx & 3;
    if (r4 == 0) rx = base;
    else if (r4 == 1) rx = cmul(base, ex);
    else if (r4 == 2) rx = cmul(base, ex2);
    else rx = cmul(base, ex3);
#pragma unroll
    for (int ky = 0; ky < 8; ky++) {
      int m = kx * 8 + ky;
      cpx bv = cmul(rx, eyp[ky]);
      const float* fc = FcB + m * 64;  // wave-uniform address
      const float* fs = FsB + m * 64;
#pragma unroll
      for (int j = 0; j < 16; j++)
        acc[j] = fmaf(bv.x, fc[j], fmaf(-bv.y, fs[j], acc[j]));
    }
  }
  // (F0 + acc) * mask
  const float* F0B = ws + OFF_F0 + (size_t)b * cC + c0;  // uniform
#pragma unroll
  for (int j = 0; j < 16; j++) acc[j] = (F0B[j] + acc[j]) * mval;
  // conv: h per-lane coalesced; wconv wave-uniform scalar
  const float* wcl = wconv + (size_t)layer * 4096 + c0;
  float* hb = h + (size_t)b * cC * cN;
#pragma unroll 4
  for (int i = 0; i < cC; i++) {
    float hv = hb[(size_t)i * cN + n];
    const float* wr = wcl + i * 64;  // uniform
#pragma unroll
    for (int j = 0; j < 16; j++) acc[j] = fmaf(hv, wr[j], acc[j]);
  }
  __syncthreads();  // all conv reads of h drained before in-place stores
  const float* bcl = bconv + layer * cC + c0;  // uniform
#pragma unroll
  for (int j = 0; j < 16; j++) {
    float v = acc[j] + bcl[j];
    if (do_gelu) v = gelu_f(v);
    hb[(size_t)(c0 + j) * cN + n] = v;
  }
}

// --- final MLP: gelu(h^T @ fc1 + b1) @ fc2 + b2
__global__ void __launch_bounds__(256) k_final(const float* __restrict__ h,
                                               const float* __restrict__ fc1_w,
                                               const float* __restrict__ fc1_b,
                                               const float* __restrict__ fc2_w,
                                               const float* __restrict__ fc2_b,
                                               float* __restrict__ out) {
  int b = blockIdx.y;
  int n0 = blockIdx.x * 64;
  int tid = threadIdx.x;
  int tn = tid & 63;
  int tg = tid >> 6;
  __shared__ __align__(16) float w1s[cC * 128];
  __shared__ __align__(16) float hT[cC * 64];
  __shared__ float red[4 * 64];
  const float* hb = h + (size_t)b * cC * cN;
#pragma unroll
  for (int i = 0; i < 16; i++) {
    int e = tid + i * 256;
    int c = e >> 6, nnx = e & 63;
    hT[c * 64 + nnx] = hb[(size_t)c * cN + n0 + nnx];
  }
#pragma unroll
  for (int i = 0; i < 32; i++) {
    int e = tid + i * 256;
    w1s[e] = fc1_w[e];
  }
  __syncthreads();
  int j0 = tg * 32;
  float acc[32] = {};
  for (int c = 0; c < cC; c++) {
    float hv = hT[c * 64 + tn];
#pragma unroll
    for (int jj = 0; jj < 32; jj += 4) {
      float4 w4 = *(const float4*)&w1s[c * 128 + j0 + jj];
      acc[jj] += hv * w4.x;
      acc[jj + 1] += hv * w4.y;
      acc[jj + 2] += hv * w4.z;
      acc[jj + 3] += hv * w4.w;
    }
  }
  float s = 0.0f;
#pragma unroll
  for (int jj = 0; jj < 32; jj++) {
    int j = j0 + jj;
    float v = gelu_f(acc[jj] + fc1_b[j]);
    s += v * fc2_w[j];
  }
  red[tg * 64 + tn] = s;
  __syncthreads();
  if (tg == 0) {
    float r = red[tn] + red[64 + tn] + red[128 + tn] + red[192 + tn] + fc2_b[0];
    out[(size_t)b * cN + n0 + tn] = r;
  }
}

extern "C" void kernel_launch(void* const* d_in, const int* in_sizes, int n_in,
                              void* d_out, int out_size, void* d_ws, size_t ws_size,
                              hipStream_t stream) {
  const float* x = (const float*)d_in[0];
  const float* fc0_w = (const float*)d_in[1];
  const float* fc0_b = (const float*)d_in[2];
  const float* wc1 = (const float*)d_in[3];
  const float* wc2 = (const float*)d_in[4];
  const float* ws1 = (const float*)d_in[5];
  const float* ws2 = (const float*)d_in[6];
  const float* w01 = (const float*)d_in[7];
  const float* w02 = (const float*)d_in[8];
  const float* wconv = (const float*)d_in[9];
  const float* bconv = (const float*)d_in[10];
  const float* fc1_w = (const float*)d_in[11];
  const float* fc1_b = (const float*)d_in[12];
  const float* fc2_w = (const float*)d_in[13];
  const float* fc2_b = (const float*)d_in[14];
  float* ws = (float*)d_ws;
  float* out = (float*)d_out;
  float* h = ws + OFF_H;

  hipLaunchKernelGGL(k_prep, dim3(cB * cN / 256), dim3(256), 0, stream, x, fc0_w, fc0_b, ws);
  for (int l = 0; l < cNL; l++) {
    hipLaunchKernelGGL(k_forward, dim3(32, cB), dim3(256), 0, stream, h, ws,
                       ws + OFF_PC, ws + OFF_PS);
    hipLaunchKernelGGL(k_reduce, dim3(512), dim3(256), 0, stream,
                       ws + OFF_PC, ws + OFF_PS, ws + OFF_XC, ws + OFF_XS);
    hipLaunchKernelGGL(k_lowrank, dim3(cB, cK), dim3(64), 0, stream, ws + OFF_XC,
                       ws + OFF_XS, wc1, wc2, ws1, ws2, w01, w02,
                       ws + OFF_FCT, ws + OFF_FST, ws + OFF_F0, l);
    hipLaunchKernelGGL(k_inverse, dim3(cN / 64, cB), dim3(256), 0, stream, h, ws,
                       wconv, bconv, l, (l != cNL - 1) ? 1 : 0);
  }
  hipLaunchKernelGGL(k_final, dim3(cN / 64, cB), dim3(256), 0, stream, h, fc1_w,
                     fc1_b, fc2_w, fc2_b, out);
}

// Round 9
// 654.095 us; speedup vs baseline: 1.3256x; 1.3256x over previous
//
#include <hip/hip_runtime.h>
#include <math.h>

namespace {
constexpr int cB = 16, cN = 8192, cC = 64, cK = 128, cR = 4, cNL = 4;
constexpr float kTwoPi = 6.28318530717958647692f;

// workspace layout (float offsets)
constexpr size_t OFF_H     = 0;                                // 8,388,608
constexpr size_t OFF_PACKA = (size_t)cB * cC * cN;             // +524,288
constexpr size_t OFF_PACKB = OFF_PACKA + (size_t)cB * cN * 4;  // +524,288
constexpr size_t OFF_PACKC = OFF_PACKB + (size_t)cB * cN * 4;  // +262,144
constexpr size_t OFF_PC    = OFF_PACKC + (size_t)cB * cN * 2;  // 512 slots * 8192
constexpr size_t OFF_PS    = OFF_PC + (size_t)512 * 8192;
constexpr size_t OFF_XC    = OFF_PS + (size_t)512 * 8192;
constexpr size_t OFF_XS    = OFF_XC + (size_t)cB * cC * cK;
constexpr size_t OFF_FCT   = OFF_XS + (size_t)cB * cC * cK;
constexpr size_t OFF_FST   = OFF_FCT + (size_t)cB * cK * cC;
constexpr size_t OFF_F0    = OFF_FST + (size_t)cB * cK * cC;
// end = 18,613,248 floats = 74.5 MB

typedef _Float16 f16x8 __attribute__((ext_vector_type(8)));
typedef _Float16 f16x4 __attribute__((ext_vector_type(4)));
typedef float f32x4 __attribute__((ext_vector_type(4)));

__device__ __forceinline__ float gelu_f(float x) {
  return 0.5f * x * (1.0f + erff(x * 0.7071067811865475244f));
}

struct cpx { float x, y; };
__device__ __forceinline__ cpx cmul(cpx a, cpx b) {
  cpx r;
  r.x = fmaf(a.x, b.x, -(a.y * b.y));
  r.y = fmaf(a.x, b.y, a.y * b.x);
  return r;
}
}  // namespace

// --- prep: fc0 into (B,C,N), per-point phase factors
__global__ void __launch_bounds__(256) k_prep(const float* __restrict__ x,
                                              const float* __restrict__ fc0_w,
                                              const float* __restrict__ fc0_b,
                                              float* __restrict__ ws) {
  int t = blockIdx.x * 256 + threadIdx.x;
  int b = t >> 13;
  int n = t & (cN - 1);
  const float* xp = x + (size_t)t * 7;
  float f0 = xp[0], f1 = xp[1], f2 = xp[2];
  float gx = xp[3], gy = xp[4], w = xp[5], m = xp[6];
  float ax = kTwoPi * gx, ay = kTwoPi * gy;
  float sx, cx, sy, cy, s8x, c8x, s4y, c4y;
  sincosf(ax, &sx, &cx);
  sincosf(ay, &sy, &cy);
  sincosf(8.0f * ax, &s8x, &c8x);
  sincosf(4.0f * ay, &s4y, &c4y);
  ((float4*)(ws + OFF_PACKA))[t] = make_float4(cx, sx, cy, sy);
  ((float4*)(ws + OFF_PACKB))[t] = make_float4(c8x, s8x, c4y, s4y);
  ((float2*)(ws + OFF_PACKC))[t] = make_float2(w * (float)cN * m, m);
  float* h = ws + OFF_H + (size_t)b * cC * cN + n;
#pragma unroll
  for (int c = 0; c < cC; c++) {
    float v = fc0_b[c] + f0 * fc0_w[c] + f1 * fc0_w[cC + c] + f2 * fc0_w[2 * cC + c];
    h[(size_t)c * cN] = v;
  }
}

// --- forward (MFMA split-fp16): per-block partial Xc/Xs, 512 blocks.
// GEMM: D[c(64), n~(256: cos128|sin128)] = sum_pts H[c,pt] * W[pt,n~]
// A-frag = H[c][pt] (lAh/lAl, [c][40]); B-frag = W staged [mode][pt] (lWh/lWl, [256][40]).
// lo operands pre-scaled x1024 into separate accumulator -> no fp16 denormal loss.
__global__ void __launch_bounds__(256, 2) k_forward(const float* __restrict__ hg,
                                                    const float* __restrict__ ws,
                                                    float* __restrict__ Pc,
                                                    float* __restrict__ Ps) {
  __shared__ __align__(16) _Float16 lAh[64 * 40];
  __shared__ __align__(16) _Float16 lAl[64 * 40];
  __shared__ __align__(16) _Float16 lWh[256 * 40];
  __shared__ __align__(16) _Float16 lWl[256 * 40];
  int b = blockIdx.y, nb = blockIdx.x;  // nb 0..31
  int n_base = nb * 256;
  int tid = threadIdx.x;
  int lane = tid & 63, w = tid >> 6;
  int l15 = lane & 15, quad = lane >> 4;
  // staging maps
  int sc = tid & 63, skg = tid >> 6;   // H: channel, 8-pt group
  int mg = tid >> 3, pg = tid & 7;     // W: 4-mode group, 4-pt group
  int kx = mg >> 1, ky0 = (mg & 1) * 4;
  const float4* pA = (const float4*)(ws + OFF_PACKA) + (size_t)b * cN;
  const float4* pB = (const float4*)(ws + OFF_PACKB) + (size_t)b * cN;
  const float2* pC = (const float2*)(ws + OFF_PACKC) + (size_t)b * cN;
  const float* hb = hg + (size_t)b * cC * cN;
  f32x4 acc0[4][4], acc1[4][4];
  f32x4 zz = {0.0f, 0.0f, 0.0f, 0.0f};
#pragma unroll
  for (int i = 0; i < 4; i++)
#pragma unroll
    for (int j = 0; j < 4; j++) { acc0[i][j] = zz; acc1[i][j] = zz; }

  for (int s = 0; s < 8; s++) {
    int n0 = n_base + s * 32;
    // --- stage H (A-operand): 64c x 32pt, hi/lo
    {
      const float* hrow = hb + (size_t)sc * cN + n0 + skg * 8;
      float4 va = *(const float4*)hrow;
      float4 vb = *(const float4*)(hrow + 4);
      float vals[8] = {va.x, va.y, va.z, va.w, vb.x, vb.y, vb.z, vb.w};
      f16x8 hi8, lo8;
#pragma unroll
      for (int e = 0; e < 8; e++) {
        _Float16 hv = (_Float16)vals[e];
        float res = vals[e] - (float)hv;
        hi8[e] = hv;
        lo8[e] = (_Float16)(res * 1024.0f);
      }
      *(f16x8*)&lAh[sc * 40 + skg * 8] = hi8;
      *(f16x8*)&lAl[sc * 40 + skg * 8] = lo8;
    }
    // --- stage W (B-operand): bases for 32 pts, 256 mode-rows, hi/lo
    {
      _Float16 chi[4][4], clo[4][4], shi[4][4], slo[4][4];  // [j][q]
#pragma unroll
      for (int q = 0; q < 4; q++) {
        int p = n0 + pg * 4 + q;
        float4 a4 = pA[p];
        float4 b4 = pB[p];
        float wsz = pC[p].x;
        cpx ex{a4.x, a4.y}, ey{a4.z, a4.w}, ex8{b4.x, b4.y}, ey4{b4.z, b4.w};
        cpx ex2 = cmul(ex, ex);
        cpx ex4v = cmul(ex2, ex2);
        cpx u{wsz, 0.0f};  // weight folded
        if (kx & 1) u = cmul(u, ex);
        if (kx & 2) u = cmul(u, ex2);
        if (kx & 4) u = cmul(u, ex4v);
        if (kx & 8) u = cmul(u, ex8);
        cpx v;
        if (ky0) v = ey4; else v = cpx{1.0f, 0.0f};
#pragma unroll
        for (int j = 0; j < 4; j++) {
          cpx m = cmul(u, v);
          _Float16 ch = (_Float16)m.x;
          chi[j][q] = ch;
          clo[j][q] = (_Float16)((m.x - (float)ch) * 1024.0f);
          _Float16 sh = (_Float16)m.y;
          shi[j][q] = sh;
          slo[j][q] = (_Float16)((m.y - (float)sh) * 1024.0f);
          v = cmul(v, ey);
        }
      }
      int mbase = kx * 8 + ky0;
#pragma unroll
      for (int j = 0; j < 4; j++) {
        int mc = mbase + j, ms = 128 + mbase + j;
        f16x4 t0 = {chi[j][0], chi[j][1], chi[j][2], chi[j][3]};
        f16x4 t1 = {clo[j][0], clo[j][1], clo[j][2], clo[j][3]};
        f16x4 t2 = {shi[j][0], shi[j][1], shi[j][2], shi[j][3]};
        f16x4 t3 = {slo[j][0], slo[j][1], slo[j][2], slo[j][3]};
        *(f16x4*)&lWh[mc * 40 + pg * 4] = t0;
        *(f16x4*)&lWl[mc * 40 + pg * 4] = t1;
        *(f16x4*)&lWh[ms * 40 + pg * 4] = t2;
        *(f16x4*)&lWl[ms * 40 + pg * 4] = t3;
      }
    }
    __syncthreads();
    // --- MFMA: wave w covers all 64 m, n~-slice [w*64, w*64+64)
    f16x8 Ahf[4], Alf[4];
#pragma unroll
    for (int mt = 0; mt < 4; mt++) {
      Ahf[mt] = *(const f16x8*)&lAh[(mt * 16 + l15) * 40 + quad * 8];
      Alf[mt] = *(const f16x8*)&lAl[(mt * 16 + l15) * 40 + quad * 8];
    }
#pragma unroll
    for (int nt = 0; nt < 4; nt++) {
      int row = w * 64 + nt * 16 + l15;
      f16x8 Bh = *(const f16x8*)&lWh[row * 40 + quad * 8];
      f16x8 Bl = *(const f16x8*)&lWl[row * 40 + quad * 8];
#pragma unroll
      for (int mt = 0; mt < 4; mt++) {
        acc0[mt][nt] = __builtin_amdgcn_mfma_f32_16x16x32_f16(Ahf[mt], Bh, acc0[mt][nt], 0, 0, 0);
        acc1[mt][nt] = __builtin_amdgcn_mfma_f32_16x16x32_f16(Ahf[mt], Bl, acc1[mt][nt], 0, 0, 0);
        acc1[mt][nt] = __builtin_amdgcn_mfma_f32_16x16x32_f16(Alf[mt], Bh, acc1[mt][nt], 0, 0, 0);
      }
    }
    __syncthreads();
  }
  // epilogue: C/D layout col=lane&15, row=(lane>>4)*4+reg
  float* pcb = Pc + (size_t)(b * 32 + nb) * 8192;
  float* psb = Ps + (size_t)(b * 32 + nb) * 8192;
  const float inv1024 = 1.0f / 1024.0f;
#pragma unroll
  for (int mt = 0; mt < 4; mt++)
#pragma unroll
    for (int nt = 0; nt < 4; nt++) {
      int nn = w * 64 + nt * 16 + l15;
      float* dst = (nn < 128) ? pcb : psb;
      int col = nn & 127;
#pragma unroll
      for (int r = 0; r < 4; r++) {
        int c = mt * 16 + quad * 4 + r;
        dst[c * 128 + col] = acc0[mt][nt][r] + acc1[mt][nt][r] * inv1024;
      }
    }
}

// --- reduce 32 partials -> Xc/Xs
__global__ void __launch_bounds__(256) k_reduce(const float* __restrict__ Pc,
                                                const float* __restrict__ Ps,
                                                float* __restrict__ Xc,
                                                float* __restrict__ Xs) {
  int idx = blockIdx.x * 256 + threadIdx.x;  // 0..131071
  int b = idx >> 13;
  int rest = idx & 8191;
  float sc = 0.0f, ss = 0.0f;
#pragma unroll
  for (int nb = 0; nb < 32; nb++) {
    sc += Pc[(size_t)(b * 32 + nb) * 8192 + rest];
    ss += Ps[(size_t)(b * 32 + nb) * 8192 + rest];
  }
  Xc[idx] = sc;
  Xs[idx] = ss;
}

// --- low-rank mixing; one wave per (b,k); butterfly reduction, no LDS
__global__ void __launch_bounds__(64) k_lowrank(const float* __restrict__ Xc,
                                                const float* __restrict__ Xs,
                                                const float* __restrict__ wc1,
                                                const float* __restrict__ wc2,
                                                const float* __restrict__ ws1,
                                                const float* __restrict__ ws2,
                                                const float* __restrict__ w01,
                                                const float* __restrict__ w02,
                                                float* __restrict__ FcT,
                                                float* __restrict__ FsT,
                                                float* __restrict__ F0, int layer) {
  int b = blockIdx.x;
  int k = blockIdx.y;
  int tid = threadIdx.x;
  const float* xcb = Xc + (size_t)b * cC * cK;
  const float* xsb = Xs + (size_t)b * cC * cK;
  float xcv = xcb[(size_t)tid * cK + k];
  float xsv = -xsb[(size_t)tid * cK + k];
  const float* c1 = wc1 + (size_t)layer * cC * cR * cK + (size_t)tid * cR * cK + k;
  const float* s1 = ws1 + (size_t)layer * cC * cR * cK + (size_t)tid * cR * cK + k;
  float A1[cR], A2[cR], B1[cR], B2[cR];
#pragma unroll
  for (int r = 0; r < cR; r++) {
    float w1c = c1[(size_t)r * cK];
    float w1sv = s1[(size_t)r * cK];
    A1[r] = xcv * w1c;
    A2[r] = xcv * w1sv;
    B1[r] = xsv * w1c;
    B2[r] = xsv * w1sv;
  }
#pragma unroll
  for (int r = 0; r < cR; r++) {
#pragma unroll
    for (int off = 32; off > 0; off >>= 1) {
      A1[r] += __shfl_xor(A1[r], off);
      A2[r] += __shfl_xor(A2[r], off);
      B1[r] += __shfl_xor(B1[r], off);
      B2[r] += __shfl_xor(B2[r], off);
    }
  }
  const float scale = 2.0f / (float)cN;
  const float* c2 = wc2 + (size_t)layer * cR * cC * cK;
  const float* s2 = ws2 + (size_t)layer * cR * cC * cK;
  int o = tid;
  float fc = 0.0f, fs = 0.0f;
#pragma unroll
  for (int r = 0; r < cR; r++) {
    float w2c = c2[((size_t)r * cC + o) * cK + k];
    float w2s = s2[((size_t)r * cC + o) * cK + k];
    fc += A1[r] * w2c - B2[r] * w2s;
    fs += B1[r] * w2c + A2[r] * w2s;
  }
  FcT[((size_t)b * cK + k) * cC + o] = scale * fc;
  FsT[((size_t)b * cK + k) * cC + o] = scale * fs;
  if (k == 0) {
    float t0[cR];
#pragma unroll
    for (int r = 0; r < cR; r++)
      t0[r] = xcv * w01[((size_t)layer * cC + tid) * cR + r];
#pragma unroll
    for (int r = 0; r < cR; r++) {
#pragma unroll
      for (int off = 32; off > 0; off >>= 1) t0[r] += __shfl_xor(t0[r], off);
    }
    float f = 0.0f;
#pragma unroll
    for (int r = 0; r < cR; r++) f += t0[r] * w02[((size_t)layer * cR + r) * cC + o];
    F0[b * cC + o] = f / (float)cN;
  }
}

// --- inverse (round-4 proven version): 128 pts/block, conflict-free 4n x 8c
__global__ void __launch_bounds__(256, 4) k_inverse(float* __restrict__ h,
                                                    const float* __restrict__ ws,
                                                    const float* __restrict__ wconv,
                                                    const float* __restrict__ bconv,
                                                    int layer, int do_gelu) {
  __shared__ __align__(16) float bc[16 * 128];  // [kl][n]; reused for wconv
  __shared__ __align__(16) float bs[16 * 128];  // [kl][n]; reused for wconv
  __shared__ __align__(16) float fcs[16 * 64];  // [kl][c]
  __shared__ __align__(16) float fss[16 * 64];
  __shared__ float msk[128];
  int b = blockIdx.y;
  int n_blk = blockIdx.x * 128;
  int tid = threadIdx.x;
  int tn = tid & 31, tc = tid >> 5;
  int n0l = tn * 4, c0 = tc * 8;
  int p = tid >> 1, t = tid & 1;
  const float4* pA = (const float4*)(ws + OFF_PACKA) + (size_t)b * cN;
  const float4* pB = (const float4*)(ws + OFF_PACKB) + (size_t)b * cN;
  const float2* pC = (const float2*)(ws + OFF_PACKC) + (size_t)b * cN;
  float4 a4 = pA[n_blk + p];
  float4 b4 = pB[n_blk + p];
  if (t == 0) msk[p] = pC[n_blk + p].y;
  cpx ex{a4.x, a4.y}, ey{a4.z, a4.w}, ex8{b4.x, b4.y}, ey4{b4.z, b4.w};
  cpx ex2 = cmul(ex, ex);
  cpx ex4 = cmul(ex2, ex2);
  cpx ex12 = cmul(ex8, ex4);
  cpx eyp[8];
  eyp[0] = {1.0f, 0.0f};
  eyp[1] = ey;
  eyp[2] = cmul(ey, ey);
  eyp[3] = cmul(eyp[2], ey);
  eyp[4] = ey4;
  eyp[5] = cmul(ey4, ey);
  eyp[6] = cmul(ey4, eyp[2]);
  eyp[7] = cmul(ey4, eyp[3]);
  const float* FcB = ws + OFF_FCT + (size_t)b * cK * cC;
  const float* FsB = ws + OFF_FST + (size_t)b * cK * cC;
  float4 pf0 = *(const float4*)&FcB[tid * 4];
  float4 pf1 = *(const float4*)&FsB[tid * 4];
  float acc[4][8] = {};
  for (int cc = 0; cc < 8; cc++) {
    __syncthreads();
    *(float4*)&fcs[tid * 4] = pf0;
    *(float4*)&fss[tid * 4] = pf1;
    cpx ra;
    if (cc == 0) ra = cpx{1.0f, 0.0f};
    else if (cc == 1) ra = ex2;
    else if (cc == 2) ra = ex4;
    else if (cc == 3) ra = cmul(ex4, ex2);
    else if (cc == 4) ra = ex8;
    else if (cc == 5) ra = cmul(ex8, ex2);
    else if (cc == 6) ra = ex12;
    else ra = cmul(ex12, ex2);
    cpx ra_odd = cmul(ra, ex);
    if (t) ra = ra_odd;
#pragma unroll
    for (int ky = 0; ky < 8; ky++) {
      cpx m = cmul(ra, eyp[ky]);
      bc[(t * 8 + ky) * 128 + p] = m.x;
      bs[(t * 8 + ky) * 128 + p] = m.y;
    }
    if (cc < 7) {
      int off = (cc + 1) * 1024;
      pf0 = *(const float4*)&FcB[off + tid * 4];
      pf1 = *(const float4*)&FsB[off + tid * 4];
    }
    __syncthreads();
#pragma unroll 2
    for (int kk = 0; kk < 16; kk++) {
      float4 b0 = *(const float4*)&bc[kk * 128 + n0l];
      float4 s0 = *(const float4*)&bs[kk * 128 + n0l];
      float4 f0 = *(const float4*)&fcs[kk * 64 + c0];
      float4 f1 = *(const float4*)&fcs[kk * 64 + c0 + 4];
      float4 g0 = *(const float4*)&fss[kk * 64 + c0];
      float4 g1 = *(const float4*)&fss[kk * 64 + c0 + 4];
      float bn[4] = {b0.x, b0.y, b0.z, b0.w};
      float sn2[4] = {s0.x, s0.y, s0.z, s0.w};
      float fcv[8] = {f0.x, f0.y, f0.z, f0.w, f1.x, f1.y, f1.z, f1.w};
      float fsv[8] = {g0.x, g0.y, g0.z, g0.w, g1.x, g1.y, g1.z, g1.w};
#pragma unroll
      for (int nq = 0; nq < 4; nq++)
#pragma unroll
        for (int j = 0; j < 8; j++)
          acc[nq][j] = fmaf(bn[nq], fcv[j], fmaf(-sn2[nq], fsv[j], acc[nq][j]));
    }
  }
  const float* F0B = ws + OFF_F0 + (size_t)b * cC;
  float4 fz0 = *(const float4*)&F0B[c0];
  float4 fz1 = *(const float4*)&F0B[c0 + 4];
  float f0v[8] = {fz0.x, fz0.y, fz0.z, fz0.w, fz1.x, fz1.y, fz1.z, fz1.w};
  float4 m0 = *(const float4*)&msk[n0l];
  float mv[4] = {m0.x, m0.y, m0.z, m0.w};
#pragma unroll
  for (int nq = 0; nq < 4; nq++)
#pragma unroll
    for (int j = 0; j < 8; j++) acc[nq][j] = (f0v[j] + acc[nq][j]) * mv[nq];
  const float* wcl = wconv + (size_t)layer * 4096;
  __syncthreads();
  {
    float4 w4 = *(const float4*)&wcl[tid * 4];
    float4 w4b = *(const float4*)&wcl[1024 + tid * 4];
    float4 w4c = *(const float4*)&wcl[2048 + tid * 4];
    float4 w4d = *(const float4*)&wcl[3072 + tid * 4];
    *(float4*)&bc[tid * 4] = w4;
    *(float4*)&bc[1024 + tid * 4] = w4b;
    *(float4*)&bs[tid * 4] = w4c;
    *(float4*)&bs[1024 + tid * 4] = w4d;
  }
  __syncthreads();
  float* hb = h + (size_t)b * cC * cN + n_blk;
  for (int i = 0; i < cC; i++) {
    float4 hv0 = *(const float4*)&hb[(size_t)i * cN + n0l];
    const float* wrow = (i < 32) ? &bc[i * 64] : &bs[(i - 32) * 64];
    float4 w0 = *(const float4*)&wrow[c0];
    float4 w1 = *(const float4*)&wrow[c0 + 4];
    float hn[4] = {hv0.x, hv0.y, hv0.z, hv0.w};
    float wv[8] = {w0.x, w0.y, w0.z, w0.w, w1.x, w1.y, w1.z, w1.w};
#pragma unroll
    for (int nq = 0; nq < 4; nq++)
#pragma unroll
      for (int j = 0; j < 8; j++) acc[nq][j] = fmaf(hn[nq], wv[j], acc[nq][j]);
  }
  __syncthreads();
#pragma unroll
  for (int j = 0; j < 8; j++) {
    int c = c0 + j;
    float bv = bconv[layer * cC + c];
    float v[4];
#pragma unroll
    for (int nq = 0; nq < 4; nq++) {
      v[nq] = acc[nq][j] + bv;
      if (do_gelu) v[nq] = gelu_f(v[nq]);
    }
    *(float4*)&hb[(size_t)c * cN + n0l] = make_float4(v[0], v[1], v[2], v[3]);
  }
}

// --- final MLP: gelu(h^T @ fc1 + b1) @ fc2 + b2
__global__ void __launch_bounds__(256) k_final(const float* __restrict__ h,
                                               const float* __restrict__ fc1_w,
                                               const float* __restrict__ fc1_b,
                                               const float* __restrict__ fc2_w,
                                               const float* __restrict__ fc2_b,
                                               float* __restrict__ out) {
  int b = blockIdx.y;
  int n0 = blockIdx.x * 64;
  int tid = threadIdx.x;
  int tn = tid & 63;
  int tg = tid >> 6;
  __shared__ __align__(16) float w1s[cC * 128];
  __shared__ __align__(16) float hT[cC * 64];
  __shared__ float red[4 * 64];
  const float* hb = h + (size_t)b * cC * cN;
#pragma unroll
  for (int i = 0; i < 16; i++) {
    int e = tid + i * 256;
    int c = e >> 6, nnx = e & 63;
    hT[c * 64 + nnx] = hb[(size_t)c * cN + n0 + nnx];
  }
#pragma unroll
  for (int i = 0; i < 32; i++) {
    int e = tid + i * 256;
    w1s[e] = fc1_w[e];
  }
  __syncthreads();
  int j0 = tg * 32;
  float acc[32] = {};
  for (int c = 0; c < cC; c++) {
    float hv = hT[c * 64 + tn];
#pragma unroll
    for (int jj = 0; jj < 32; jj += 4) {
      float4 w4 = *(const float4*)&w1s[c * 128 + j0 + jj];
      acc[jj] += hv * w4.x;
      acc[jj + 1] += hv * w4.y;
      acc[jj + 2] += hv * w4.z;
      acc[jj + 3] += hv * w4.w;
    }
  }
  float s = 0.0f;
#pragma unroll
  for (int jj = 0; jj < 32; jj++) {
    int j = j0 + jj;
    float v = gelu_f(acc[jj] + fc1_b[j]);
    s += v * fc2_w[j];
  }
  red[tg * 64 + tn] = s;
  __syncthreads();
  if (tg == 0) {
    float r = red[tn] + red[64 + tn] + red[128 + tn] + red[192 + tn] + fc2_b[0];
    out[(size_t)b * cN + n0 + tn] = r;
  }
}

extern "C" void kernel_launch(void* const* d_in, const int* in_sizes, int n_in,
                              void* d_out, int out_size, void* d_ws, size_t ws_size,
                              hipStream_t stream) {
  const float* x = (const float*)d_in[0];
  const float* fc0_w = (const float*)d_in[1];
  const float* fc0_b = (const float*)d_in[2];
  const float* wc1 = (const float*)d_in[3];
  const float* wc2 = (const float*)d_in[4];
  const float* ws1 = (const float*)d_in[5];
  const float* ws2 = (const float*)d_in[6];
  const float* w01 = (const float*)d_in[7];
  const float* w02 = (const float*)d_in[8];
  const float* wconv = (const float*)d_in[9];
  const float* bconv = (const float*)d_in[10];
  const float* fc1_w = (const float*)d_in[11];
  const float* fc1_b = (const float*)d_in[12];
  const float* fc2_w = (const float*)d_in[13];
  const float* fc2_b = (const float*)d_in[14];
  float* ws = (float*)d_ws;
  float* out = (float*)d_out;
  float* h = ws + OFF_H;

  hipLaunchKernelGGL(k_prep, dim3(cB * cN / 256), dim3(256), 0, stream, x, fc0_w, fc0_b, ws);
  for (int l = 0; l < cNL; l++) {
    hipLaunchKernelGGL(k_forward, dim3(32, cB), dim3(256), 0, stream, h, ws,
                       ws + OFF_PC, ws + OFF_PS);
    hipLaunchKernelGGL(k_reduce, dim3(512), dim3(256), 0, stream,
                       ws + OFF_PC, ws + OFF_PS, ws + OFF_XC, ws + OFF_XS);
    hipLaunchKernelGGL(k_lowrank, dim3(cB, cK), dim3(64), 0, stream, ws + OFF_XC,
                       ws + OFF_XS, wc1, wc2, ws1, ws2, w01, w02,
                       ws + OFF_FCT, ws + OFF_FST, ws + OFF_F0, l);
    hipLaunchKernelGGL(k_inverse, dim3(cN / 128, cB), dim3(256), 0, stream, h, ws,
                       wconv, bconv, l, (l != cNL - 1) ? 1 : 0);
  }
  hipLaunchKernelGGL(k_final, dim3(cN / 64, cB), dim3(256), 0, stream, h, fc1_w,
                     fc1_b, fc2_w, fc2_b, out);
}